// Round 2
// baseline (3470.559 us; speedup 1.0000x reference)
//
#include <hip/hip_runtime.h>
#include <cmath>

// ---------- helpers: order-preserving float<->uint for atomicMax ----------
// encf never returns 0 for non-NaN inputs, so 0 is the "empty" marker.
__device__ __forceinline__ unsigned encf(float f) {
    unsigned u = __float_as_uint(f);
    return (u & 0x80000000u) ? ~u : (u | 0x80000000u);
}
__device__ __forceinline__ float decf(unsigned v) {
    unsigned u = (v & 0x80000000u) ? (v ^ 0x80000000u) : ~v;
    return __uint_as_float(u);
}

// ---------- K0: encoder. one wave per node. lane = output dim ----------
// nbuf = relu(x@Wn+bn); acc1 = nbuf@Wroot1 + b1 (root/self term of layer 1)
__global__ __launch_bounds__(64) void k_encoder(
    const float* __restrict__ x,
    const float* __restrict__ Wn, const float* __restrict__ bn,
    const float* __restrict__ Wroot1, const float* __restrict__ b1,
    float* __restrict__ nbuf, float* __restrict__ acc1)
{
    int i = blockIdx.x;
    int j = threadIdx.x;
    __shared__ __align__(16) float nS[64];
    float x0 = x[3*i], x1 = x[3*i+1], x2 = x[3*i+2];
    float nj = fmaxf(fmaf(x2, Wn[128+j], fmaf(x1, Wn[64+j], fmaf(x0, Wn[j], bn[j]))), 0.f);
    size_t o64 = (size_t)i*64 + j;
    nbuf[o64] = nj;
    nS[j] = nj;
    __syncthreads();
    float acc = b1[j];
    const float4* n4 = (const float4*)nS;
    #pragma unroll
    for (int c = 0; c < 16; ++c) {
        float4 f = n4[c];
        acc = fmaf(f.x, Wroot1[(4*c+0)*64+j], acc);
        acc = fmaf(f.y, Wroot1[(4*c+1)*64+j], acc);
        acc = fmaf(f.z, Wroot1[(4*c+2)*64+j], acc);
        acc = fmaf(f.w, Wroot1[(4*c+3)*64+j], acc);
    }
    acc1[o64] = acc;
}

// ---------- K-init: zero Mr (uint [N*64]), perm=-1, cnt=0 ----------
__global__ void k_init(unsigned* __restrict__ Mr, int* __restrict__ perm,
                       int* __restrict__ cnt, size_t mrn, int nslots)
{
    size_t gid = (size_t)blockIdx.x*blockDim.x + threadIdx.x;
    size_t stride = (size_t)gridDim.x*blockDim.x;
    uint4* M4 = (uint4*)Mr;
    size_t m4 = mrn >> 2;
    for (size_t k = gid; k < m4; k += stride) M4[k] = make_uint4(0,0,0,0);
    for (size_t k = gid; k < (size_t)nslots; k += stride) perm[k] = -1;
    if (gid < 8) cnt[gid] = 0;
}

// ---------- bucket edges by relation ----------
__global__ void k_hist(const int* __restrict__ et, int* __restrict__ cnt, int E)
{
    __shared__ int h[8];
    if (threadIdx.x < 8) h[threadIdx.x] = 0;
    __syncthreads();
    int gid = blockIdx.x*blockDim.x + threadIdx.x;
    int stride = gridDim.x*blockDim.x;
    for (int e = gid; e < E; e += stride) atomicAdd(&h[et[e]], 1);
    __syncthreads();
    if (threadIdx.x < 8) atomicAdd(&cnt[threadIdx.x], h[threadIdx.x]);
}

__global__ void k_scan(const int* __restrict__ cnt, int* __restrict__ cursor, int EPB)
{
    if (threadIdx.x == 0) {
        int o = 0;
        for (int r = 0; r < 8; ++r) {
            cursor[r] = o;
            int c = cnt[r];
            o += ((c + EPB - 1)/EPB)*EPB;   // pad each segment to EPB multiple
        }
    }
}

__global__ void k_scatter(const int* __restrict__ et, int* __restrict__ cursor,
                          int* __restrict__ perm, int E)
{
    __shared__ int h[8];
    __shared__ int base8[8];
    if (threadIdx.x < 8) h[threadIdx.x] = 0;
    __syncthreads();
    int e = blockIdx.x*blockDim.x + threadIdx.x;
    int r = 0, lpos = 0;
    bool act = (e < E);
    if (act) { r = et[e]; lpos = atomicAdd(&h[r], 1); }
    __syncthreads();
    if (threadIdx.x < 8)
        base8[threadIdx.x] = (h[threadIdx.x] > 0) ? atomicAdd(&cursor[threadIdx.x], h[threadIdx.x]) : 0;
    __syncthreads();
    if (act) perm[base8[r] + lpos] = e;
}

// ---------- K1: layer-1 edge pass. 1 wave/block, 128 edges/block, single relation.
// lane j holds column j of W1[r] (96 regs). feat = [n[src] || e]. atomicAdd to acc1[dst].
__global__ __launch_bounds__(64) void k_edge1(
    const int* __restrict__ perm, const int* __restrict__ ei, const int* __restrict__ et,
    const float* __restrict__ ea, const float* __restrict__ nbuf,
    const float* __restrict__ W1, const float* __restrict__ We, const float* __restrict__ be,
    float* __restrict__ acc1, int E)
{
    int lane = threadIdx.x;
    int base = blockIdx.x * 128;
    __shared__ __align__(16) float eS[32];
    int p0 = perm[base];
    if (p0 < 0) return;                      // whole 128-window is padding
    int r0 = et[p0];
    float w[96];
    {
        const float* Wb = W1 + (size_t)r0*96*64 + lane;
        #pragma unroll
        for (int k = 0; k < 96; ++k) w[k] = Wb[k*64];
    }
    float we0 = We[lane & 31], we1 = We[32 + (lane & 31)], bev = be[lane & 31];
    for (int chunk = 0; chunk < 2; ++chunk) {
        int slot = base + chunk*64 + lane;
        int myeid = perm[slot];
        int msrc = 0, mdst = 0; float ma0 = 0.f, ma1 = 0.f;
        if (myeid >= 0) {
            msrc = ei[myeid];
            mdst = ei[E + myeid];
            ma0 = ea[2*myeid];
            ma1 = ea[2*myeid + 1];
        }
        for (int i = 0; i < 64; ++i) {
            int eid = __shfl(myeid, i);
            if (eid < 0) break;              // padding is contiguous at segment tail
            int src = __shfl(msrc, i);
            int dst = __shfl(mdst, i);
            float a0 = __shfl(ma0, i);
            float a1 = __shfl(ma1, i);
            if (lane < 32) eS[lane] = fmaxf(fmaf(a1, we1, fmaf(a0, we0, bev)), 0.f);
            __syncthreads();
            const float4* n4 = (const float4*)(nbuf + (size_t)src*64);
            float acc = 0.f;
            #pragma unroll
            for (int c = 0; c < 16; ++c) {
                float4 f = n4[c];            // all lanes same addr -> broadcast
                acc = fmaf(f.x, w[4*c+0], acc);
                acc = fmaf(f.y, w[4*c+1], acc);
                acc = fmaf(f.z, w[4*c+2], acc);
                acc = fmaf(f.w, w[4*c+3], acc);
            }
            const float4* e4 = (const float4*)eS;
            #pragma unroll
            for (int c = 0; c < 8; ++c) {
                float4 f = e4[c];
                acc = fmaf(f.x, w[64+4*c+0], acc);
                acc = fmaf(f.y, w[64+4*c+1], acc);
                acc = fmaf(f.z, w[64+4*c+2], acc);
                acc = fmaf(f.w, w[64+4*c+3], acc);
            }
            __syncthreads();
            atomicAdd(acc1 + (size_t)dst*64 + lane, acc);
        }
    }
}

// ---------- K2: fused relu + root2. acc1 -> h (in place); acc2(nbuf) = h@Wroot2+b2 ----------
__global__ __launch_bounds__(64) void k_hrow(
    float* __restrict__ acc1, float* __restrict__ acc2,
    const float* __restrict__ Wroot2, const float* __restrict__ b2)
{
    int i = blockIdx.x, j = threadIdx.x;
    __shared__ __align__(16) float hS[64];
    size_t o64 = (size_t)i*64 + j;
    float h = fmaxf(acc1[o64], 0.f);
    acc1[o64] = h;
    hS[j] = h;
    __syncthreads();
    float acc = b2[j];
    const float4* h4 = (const float4*)hS;
    #pragma unroll
    for (int c = 0; c < 16; ++c) {
        float4 f = h4[c];
        acc = fmaf(f.x, Wroot2[(4*c+0)*64+j], acc);
        acc = fmaf(f.y, Wroot2[(4*c+1)*64+j], acc);
        acc = fmaf(f.z, Wroot2[(4*c+2)*64+j], acc);
        acc = fmaf(f.w, Wroot2[(4*c+3)*64+j], acc);
    }
    acc2[o64] = acc;
}

// ---------- K3: layer-2 edge pass for ONE relation. atomicMax into Mr ----------
__global__ __launch_bounds__(64) void k_edge2r(
    const int* __restrict__ perm, const int* __restrict__ ei, const int* __restrict__ et,
    const float* __restrict__ hbuf, const float* __restrict__ W2,
    unsigned* __restrict__ Mr, int E, int rel)
{
    int lane = threadIdx.x;
    int base = blockIdx.x * 128;
    int p0 = perm[base];
    if (p0 < 0) return;
    int r0 = et[p0];
    if (r0 != rel) return;                   // not this relation's segment
    float w[64];
    {
        const float* Wb = W2 + (size_t)r0*64*64 + lane;
        #pragma unroll
        for (int k = 0; k < 64; ++k) w[k] = Wb[k*64];
    }
    for (int chunk = 0; chunk < 2; ++chunk) {
        int slot = base + chunk*64 + lane;
        int myeid = perm[slot];
        int msrc = 0, mdst = 0;
        if (myeid >= 0) { msrc = ei[myeid]; mdst = ei[E + myeid]; }
        for (int i = 0; i < 64; ++i) {
            int eid = __shfl(myeid, i);
            if (eid < 0) break;
            int src = __shfl(msrc, i);
            int dst = __shfl(mdst, i);
            const float4* h4 = (const float4*)(hbuf + (size_t)src*64);
            float acc = 0.f;
            #pragma unroll
            for (int c = 0; c < 16; ++c) {
                float4 f = h4[c];
                acc = fmaf(f.x, w[4*c+0], acc);
                acc = fmaf(f.y, w[4*c+1], acc);
                acc = fmaf(f.z, w[4*c+2], acc);
                acc = fmaf(f.w, w[4*c+3], acc);
            }
            atomicMax(Mr + (size_t)dst*64 + lane, encf(acc));
        }
    }
}

// ---------- K-merge: acc2 += decode(Mr); optionally re-zero Mr for next relation ----------
__global__ void k_merge(unsigned* __restrict__ Mr, float* __restrict__ acc2,
                        size_t n, int zeroNext)
{
    size_t gid = (size_t)blockIdx.x*blockDim.x + threadIdx.x;
    size_t stride = (size_t)gridDim.x*blockDim.x;
    for (size_t k = gid; k < n; k += stride) {
        unsigned v = Mr[k];
        if (zeroNext) Mr[k] = 0u;
        if (v) acc2[k] += decf(v);           // v==0 <=> no edge of this relation -> +0
    }
}

// ---------- K4: h2 = relu(acc2); o = relu(omega@Wo+bo); head ----------
__global__ __launch_bounds__(64) void k_final(
    const float* __restrict__ acc2, const float* __restrict__ omega,
    const float* __restrict__ Wo, const float* __restrict__ bo,
    const float* __restrict__ Wagg, const float* __restrict__ bagg,
    const float* __restrict__ Wc, const float* __restrict__ bc,
    float* __restrict__ out)
{
    int i = blockIdx.x, j = threadIdx.x;
    __shared__ __align__(16) float cS[128];
    float om0 = omega[2*i], om1 = omega[2*i+1];
    float oj = fmaxf(fmaf(om1, Wo[64+j], fmaf(om0, Wo[j], bo[j])), 0.f);
    float h2 = fmaxf(acc2[(size_t)i*64 + j], 0.f);
    cS[j] = h2;
    cS[64 + j] = oj;
    __syncthreads();
    float t = bagg[j];
    const float4* c4 = (const float4*)cS;
    #pragma unroll
    for (int c = 0; c < 32; ++c) {
        float4 f = c4[c];
        t = fmaf(f.x, Wagg[(4*c+0)*64+j], t);
        t = fmaf(f.y, Wagg[(4*c+1)*64+j], t);
        t = fmaf(f.z, Wagg[(4*c+2)*64+j], t);
        t = fmaf(f.w, Wagg[(4*c+3)*64+j], t);
    }
    t = fmaxf(t, 0.f);
    float part = t * Wc[j];
    #pragma unroll
    for (int off = 32; off; off >>= 1) part += __shfl_xor(part, off);
    if (j == 0) out[i] = tanhf(part + bc[0]) * 5.0f;
}

extern "C" void kernel_launch(void* const* d_in, const int* in_sizes, int n_in,
                              void* d_out, int out_size, void* d_ws, size_t ws_size,
                              hipStream_t stream)
{
    const float* x      = (const float*)d_in[0];
    const int*   ei     = (const int*)d_in[1];
    const float* ea     = (const float*)d_in[2];
    const int*   et     = (const int*)d_in[3];
    const float* omega  = (const float*)d_in[4];
    const float* Wn     = (const float*)d_in[5];
    const float* bn     = (const float*)d_in[6];
    const float* We     = (const float*)d_in[7];
    const float* be     = (const float*)d_in[8];
    const float* Wo     = (const float*)d_in[9];
    const float* bo     = (const float*)d_in[10];
    const float* W1     = (const float*)d_in[11];
    const float* Wroot1 = (const float*)d_in[12];
    const float* b1     = (const float*)d_in[13];
    const float* W2     = (const float*)d_in[14];
    const float* Wroot2 = (const float*)d_in[15];
    const float* b2     = (const float*)d_in[16];
    const float* Wagg   = (const float*)d_in[17];
    const float* bagg   = (const float*)d_in[18];
    const float* Wc     = (const float*)d_in[19];
    const float* bc     = (const float*)d_in[20];
    int N = in_sizes[0] / 3;
    int E = in_sizes[3];
    float* out = (float*)d_out;

    // ---- workspace layout (lean: ~83 MB for N=100K, E=1.6M) ----
    float*    nbuf = (float*)d_ws;                      // [N,64] n; reused as acc2
    float*    acc1 = nbuf + (size_t)N*64;               // [N,64] acc1 -> h
    unsigned* Mr   = (unsigned*)(acc1 + (size_t)N*64);  // [N,64] per-relation max buffer
    int nslots = ((E + 127)/128 + 8) * 128;             // padded slot upper bound
    int* perm   = (int*)(Mr + (size_t)N*64);            // [nslots]
    int* cnt    = perm + nslots;                        // [8]
    int* cursor = cnt + 8;                              // [8]
    float* acc2 = nbuf;                                 // alias (n dead after k_edge1)

    int eblocks = nslots / 128;

    k_encoder<<<N, 64, 0, stream>>>(x, Wn, bn, Wroot1, b1, nbuf, acc1);
    k_init<<<1024, 256, 0, stream>>>(Mr, perm, cnt, (size_t)N*64, nslots);
    k_hist<<<1024, 256, 0, stream>>>(et, cnt, E);
    k_scan<<<1, 64, 0, stream>>>(cnt, cursor, 128);
    k_scatter<<<(E + 255)/256, 256, 0, stream>>>(et, cursor, perm, E);
    k_edge1<<<eblocks, 64, 0, stream>>>(perm, ei, et, ea, nbuf, W1, We, be, acc1, E);
    k_hrow<<<N, 64, 0, stream>>>(acc1, acc2, Wroot2, b2);
    for (int r = 0; r < 8; ++r) {
        k_edge2r<<<eblocks, 64, 0, stream>>>(perm, ei, et, acc1, W2, Mr, E, r);
        k_merge<<<1024, 256, 0, stream>>>(Mr, acc2, (size_t)N*64, (r < 7) ? 1 : 0);
    }
    k_final<<<N, 64, 0, stream>>>(acc2, omega, Wo, bo, Wagg, bagg, Wc, bc, out);
}